// Round 6
// baseline (623.084 us; speedup 1.0000x reference)
//
#include <hip/hip_runtime.h>
#include <math.h>

// ---------------------------------------------------------------------------
// GNN: 2x TransformerConv(heads=1) + fused GCNConv(mu)/GCNConv(logstd)
// N=50000, E=1.6M.
// e = ea@We enters score as (q@We^T).ea and aggregation as (sum(alpha*ea))@We.
// q@We^T folded into the packed MFMA GEMM. Edge loop touches only 16-dim bf16
// ea (CSR-streamed, nontemporal) + packed bf16 k/v (L2-resident gather).
// Padded CSR (multiple of 16, sentinel src=N with zero KV row, ea=0): pads
// contribute exactly exp(0)=1 to the softmax denominator -> subtract npad.
// No masking, no tails, no shuffle broadcast of src, 32-bit addressing.
// ---------------------------------------------------------------------------

#define TPB 256
typedef unsigned int uint32;
typedef unsigned short u16;
typedef __attribute__((ext_vector_type(4))) float f32x4;
typedef __attribute__((ext_vector_type(8))) short bf16x8;

__device__ __forceinline__ uint32 f2bf(float f) {   // RNE fp32 -> bf16 bits
    uint32 u = __float_as_uint(f);
    return (u + 0x7fffu + ((u >> 16) & 1u)) >> 16;
}
__device__ __forceinline__ float bf2f(uint32 b) { return __uint_as_float(b << 16); }

// ---------------- CSR build (padded) ----------------
__global__ void hist_kernel(const int* __restrict__ dst, int* __restrict__ deg, int E) {
    int i = blockIdx.x * TPB + threadIdx.x;
    if (i < E) atomicAdd(&deg[__builtin_nontemporal_load(dst + i)], 1);
}

// pass 1: per-block inclusive scan of PADDED degrees ((deg+15)&~15)
__global__ __launch_bounds__(1024) void scan1_kernel(const int* __restrict__ deg,
                                                     int* __restrict__ prowp,
                                                     int* __restrict__ bsum, int n) {
    __shared__ int wsum[16];
    __shared__ int woff[16];
    int tid = threadIdx.x;
    int i = blockIdx.x * 1024 + tid;
    int lane = tid & 63, w = tid >> 6;
    int dg = (i < n) ? deg[i] : 0;
    int x = (dg + 15) & ~15;
    int v = x;
#pragma unroll
    for (int off = 1; off < 64; off <<= 1) {
        int t = __shfl_up(v, off, 64);
        if (lane >= off) v += t;
    }
    if (lane == 63) wsum[w] = v;
    __syncthreads();
    if (tid < 64) {
        int s = (tid < 16) ? wsum[tid] : 0;
#pragma unroll
        for (int off = 1; off < 16; off <<= 1) {
            int t = __shfl_up(s, off, 64);
            if (lane >= off) s += t;
        }
        if (tid < 16) woff[tid] = s;
    }
    __syncthreads();
    int incl = v + (w ? woff[w - 1] : 0);
    if (i < n) prowp[i] = incl;
    if (tid == 1023) bsum[blockIdx.x] = incl;
}

// pass 2: single wave scans block sums (nb <= 64); also writes total to prowp[N]
__global__ void scan2_kernel(const int* __restrict__ bsum, int* __restrict__ boff,
                             int* __restrict__ prowpN, int nb) {
    int tid = threadIdx.x;
    int x = (tid < nb) ? bsum[tid] : 0;
    int v = x;
#pragma unroll
    for (int off = 1; off < 64; off <<= 1) {
        int t = __shfl_up(v, off, 64);
        if (tid >= off) v += t;
    }
    if (tid < nb) boff[tid] = v - x;
    if (tid == nb - 1) *prowpN = v;
}

// pass 3: finalize prowp (global exclusive), cursor, dinv
__global__ __launch_bounds__(1024) void scan3_kernel(const int* __restrict__ deg,
                                                     const int* __restrict__ boff,
                                                     int* __restrict__ prowp,
                                                     int* __restrict__ cursor,
                                                     float* __restrict__ dinv, int n) {
    int i = blockIdx.x * 1024 + threadIdx.x;
    if (i < n) {
        int dg = deg[i];
        int x = (dg + 15) & ~15;
        int excl = prowp[i] - x + boff[blockIdx.x];
        prowp[i] = excl;
        cursor[i] = excl;
        dinv[i] = 1.0f / sqrtf((float)(dg + 1));
    }
}

// scatter edges into padded CSR order; permute+convert EA -> bf16 EAb
__global__ void scatter_kernel(const int* __restrict__ src, const int* __restrict__ dst,
                               const float* __restrict__ EA,
                               int* __restrict__ cursor,
                               int* __restrict__ psrc, u16* __restrict__ EAb, int E) {
    int i = blockIdx.x * TPB + threadIdx.x;
    if (i >= E) return;
    int pos = atomicAdd(&cursor[__builtin_nontemporal_load(dst + i)], 1);
    __builtin_nontemporal_store(__builtin_nontemporal_load(src + i), psrc + pos);
    const f32x4* e4 = (const f32x4*)(EA + (size_t)i * 16);
    f32x4 a = __builtin_nontemporal_load(e4);
    f32x4 b = __builtin_nontemporal_load(e4 + 1);
    f32x4 c = __builtin_nontemporal_load(e4 + 2);
    f32x4 d = __builtin_nontemporal_load(e4 + 3);
    uint32* o = (uint32*)(EAb + (size_t)pos * 16);
    uint32 w0 = f2bf(a.x) | (f2bf(a.y) << 16);
    uint32 w1 = f2bf(a.z) | (f2bf(a.w) << 16);
    uint32 w2 = f2bf(b.x) | (f2bf(b.y) << 16);
    uint32 w3 = f2bf(b.z) | (f2bf(b.w) << 16);
    uint32 w4 = f2bf(c.x) | (f2bf(c.y) << 16);
    uint32 w5 = f2bf(c.z) | (f2bf(c.w) << 16);
    uint32 w6 = f2bf(d.x) | (f2bf(d.y) << 16);
    uint32 w7 = f2bf(d.z) | (f2bf(d.w) << 16);
    __builtin_nontemporal_store(w0, o + 0);
    __builtin_nontemporal_store(w1, o + 1);
    __builtin_nontemporal_store(w2, o + 2);
    __builtin_nontemporal_store(w3, o + 3);
    __builtin_nontemporal_store(w4, o + 4);
    __builtin_nontemporal_store(w5, o + 5);
    __builtin_nontemporal_store(w6, o + 6);
    __builtin_nontemporal_store(w7, o + 7);
}

// fill pad slots: psrc=N (zero KV row), ea = 0
__global__ void padfill_kernel(const int* __restrict__ prowp, const int* __restrict__ deg,
                               int* __restrict__ psrc, u16* __restrict__ EAb, int N) {
    int n = blockIdx.x * TPB + threadIdx.x;
    if (n >= N) return;
    int p = prowp[n] + deg[n], pe = prowp[n + 1];
    for (; p < pe; ++p) {
        psrc[p] = N;
        uint32* o = (uint32*)(EAb + (size_t)p * 16);
#pragma unroll
        for (int j = 0; j < 8; ++j) o[j] = 0u;
    }
}

// ---------------- weight packing (bf16, transposed [c][k], fused QE/scale) --
__global__ void pack_kernel(
    const float* Wq1, const float* Wk1, const float* Wv1, const float* Ws1,
    const float* bq1, const float* bk1, const float* bv1, const float* bs1,
    const float* We1,
    const float* Wq2, const float* Wk2, const float* Wv2, const float* Ws2,
    const float* bq2, const float* bk2, const float* bv2, const float* bs2,
    const float* We2,
    const float* Wmu, const float* bmu, const float* Wls, const float* bls,
    const float* x, unsigned short* xb, int NX,
    unsigned short* Wc1t, float* bc1, unsigned short* Wc2t, float* bc2,
    float* Wc3, float* bc3) {
    const float s1 = 0.1020620726159658f;  // 1/sqrt(96)
    const float s2 = 0.125f;               // 1/sqrt(64)
    int gi = blockIdx.x * TPB + threadIdx.x;
    const int R0 = 448 * 128, R1 = R0 + 320 * 96, R2 = R1 + 64 * 64;
    const int R3 = R2 + 448, R4 = R3 + 320, R5 = R4 + 64;
    for (int i = gi; i < R5; i += gridDim.x * TPB) {
        if (i < R0) {                       // Wc1t[c][kk]
            int c = i / 128, kk = i % 128;
            float v = 0.f;
            if (c < 96) v = Wq1[kk * 96 + c] * s1;
            else if (c < 112) {
                int t = c - 96; float a = 0.f;
                for (int u = 0; u < 96; ++u) a += Wq1[kk * 96 + u] * We1[t * 96 + u];
                v = a * s1;
            } else if (c < 304) {
                int tt = c - 112;
                v = (tt & 1) ? Wv1[kk * 96 + (tt >> 1)] : Wk1[kk * 96 + (tt >> 1)];
            } else if (c < 400) v = Ws1[kk * 96 + (c - 304)];
            Wc1t[i] = (unsigned short)f2bf(v);
        } else if (i < R1) {                // Wc2t[c][kk]
            int j = i - R0;
            int c = j / 96, kk = j % 96;
            float v = 0.f;
            if (c < 64) v = Wq2[kk * 64 + c] * s2;
            else if (c < 80) {
                int t = c - 64; float a = 0.f;
                for (int u = 0; u < 64; ++u) a += Wq2[kk * 64 + u] * We2[t * 64 + u];
                v = a * s2;
            } else if (c < 208) {
                int tt = c - 80;
                v = (tt & 1) ? Wv2[kk * 64 + (tt >> 1)] : Wk2[kk * 64 + (tt >> 1)];
            } else if (c < 272) v = Ws2[kk * 64 + (c - 208)];
            Wc2t[j] = (unsigned short)f2bf(v);
        } else if (i < R2) {                // Wc3[k][c] fp32
            int j = i - R1;
            int k = j / 64, c = j % 64;
            Wc3[j] = (c < 32) ? Wmu[k * 32 + c] : Wls[k * 32 + (c - 32)];
        } else if (i < R3) {                // bc1
            int c = i - R2;
            float v = 0.f;
            if (c < 96) v = bq1[c] * s1;
            else if (c < 112) {
                int t = c - 96; float a = 0.f;
                for (int u = 0; u < 96; ++u) a += bq1[u] * We1[t * 96 + u];
                v = a * s1;
            } else if (c < 304) {
                int tt = c - 112;
                v = (tt & 1) ? bv1[tt >> 1] : bk1[tt >> 1];
            } else if (c < 400) v = bs1[c - 304];
            bc1[c] = v;
        } else if (i < R4) {                // bc2
            int c = i - R3;
            float v = 0.f;
            if (c < 64) v = bq2[c] * s2;
            else if (c < 80) {
                int t = c - 64; float a = 0.f;
                for (int u = 0; u < 64; ++u) a += bq2[u] * We2[t * 64 + u];
                v = a * s2;
            } else if (c < 208) {
                int tt = c - 80;
                v = (tt & 1) ? bv2[tt >> 1] : bk2[tt >> 1];
            } else if (c < 272) v = bs2[c - 208];
            bc2[c] = v;
        } else {                            // bc3
            int c = i - R4;
            bc3[c] = (c < 32) ? bmu[c] : bls[c - 32];
        }
    }
    for (int i = gi; i < NX; i += gridDim.x * TPB)
        xb[i] = (unsigned short)f2bf(x[i]);
}

// ---------------- MFMA bf16 GEMM with region epilogue ----------------------
__global__ __launch_bounds__(256) void mfma_gemm_kernel(
    const unsigned short* __restrict__ A,   // [N,K] bf16
    const unsigned short* __restrict__ Wt,  // [Cpad,K] bf16 (transposed)
    const float* __restrict__ bias,         // [Cpad]
    float* __restrict__ Qs, float* __restrict__ QE,
    uint32* __restrict__ KVp, float* __restrict__ SK,
    int N, int K, int Cq) {
    __shared__ unsigned short As[64][56];
    __shared__ unsigned short Bs[64][56];
    int r0 = blockIdx.x * 64, c0 = blockIdx.y * 64;
    int tid = threadIdx.x;
    int lane = tid & 63, w = tid >> 6;
    int wm = w >> 1, wn = w & 1;
    int l15 = lane & 15, l4 = lane >> 4;
    f32x4 zero = {0.f, 0.f, 0.f, 0.f};
    f32x4 acc[2][2] = {{zero, zero}, {zero, zero}};
    int sr = tid >> 2, sk = (tid & 3) * 8;

    for (int kc = 0; kc < K; kc += 32) {
        bf16x8 av = {};
        int ar = r0 + sr;
        if (ar < N) av = *(const bf16x8*)(A + (size_t)ar * K + kc + sk);
        *(bf16x8*)&As[sr][sk] = av;
        bf16x8 bv = *(const bf16x8*)(Wt + (size_t)(c0 + sr) * K + kc + sk);
        *(bf16x8*)&Bs[sr][sk] = bv;
        __syncthreads();
        bf16x8 af0 = *(const bf16x8*)&As[32 * wm + l15][l4 * 8];
        bf16x8 af1 = *(const bf16x8*)&As[32 * wm + 16 + l15][l4 * 8];
        bf16x8 bf0 = *(const bf16x8*)&Bs[32 * wn + l15][l4 * 8];
        bf16x8 bf1 = *(const bf16x8*)&Bs[32 * wn + 16 + l15][l4 * 8];
        acc[0][0] = __builtin_amdgcn_mfma_f32_16x16x32_bf16(af0, bf0, acc[0][0], 0, 0, 0);
        acc[0][1] = __builtin_amdgcn_mfma_f32_16x16x32_bf16(af0, bf1, acc[0][1], 0, 0, 0);
        acc[1][0] = __builtin_amdgcn_mfma_f32_16x16x32_bf16(af1, bf0, acc[1][0], 0, 0, 0);
        acc[1][1] = __builtin_amdgcn_mfma_f32_16x16x32_bf16(af1, bf1, acc[1][1], 0, 0, 0);
        __syncthreads();
    }

    int qe0 = Cq, kv0 = Cq + 16, sk0 = 3 * Cq + 16, end0 = 4 * Cq + 16;
#pragma unroll
    for (int fm = 0; fm < 2; ++fm) {
#pragma unroll
        for (int fn = 0; fn < 2; ++fn) {
            int cb = c0 + 32 * wn + 16 * fn;
            int c = cb + l15;
            float bia = bias[c];
#pragma unroll
            for (int r = 0; r < 4; ++r) {
                int row = r0 + 32 * wm + 16 * fm + l4 * 4 + r;
                float v = acc[fm][fn][r] + bia;
                float pv = __shfl_xor(v, 1, 64);
                bool ok = row < N;
                if (cb < qe0) {
                    if (ok) Qs[(size_t)row * Cq + c] = v;
                } else if (cb < kv0) {
                    if (ok) QE[(size_t)row * 16 + (c - qe0)] = v;
                } else if (cb < sk0) {
                    if (ok && !(l15 & 1)) {
                        int t = c - kv0;
                        KVp[(size_t)row * Cq + (t >> 1)] = (f2bf(v) << 16) | f2bf(pv);
                    }
                } else if (cb < end0) {
                    if (ok) SK[(size_t)row * Cq + (c - sk0)] = v;
                }
            }
        }
    }
}

// ---------------- fused edge attention (padded CSR, mask-free) -------------
// One wave per dst; halves take interleaved 8-edge groups. Pads (src=N,
// ea=0) contribute exp(0)=1 to d -> subtract npad after the merge.
template <int C>
__global__ __launch_bounds__(256) void edge_attn_kernel(
    const float* __restrict__ Qs, const float* __restrict__ SK,
    const uint32* __restrict__ KVp,
    const u16* __restrict__ EAb, const float* __restrict__ QE,
    const int* __restrict__ prowp, const int* __restrict__ deg,
    const int* __restrict__ psrc,
    float* __restrict__ Hpre, float* __restrict__ AEA, int N) {
    constexpr int CPL = C / 32;
    int n = blockIdx.x * 4 + (threadIdx.x >> 6);
    if (n >= N) return;
    int lane = threadIdx.x & 63;
    int half = lane >> 5, l = lane & 31, t16 = l & 15;
    bool lo16 = (l < 16);

    uint32 nC = (uint32)n * C;
    float q[CPL], acc[CPL];
#pragma unroll
    for (int j = 0; j < CPL; ++j) { q[j] = Qs[nC + l + 32 * j]; acc[j] = 0.f; }
    float qe = lo16 ? QE[(uint32)n * 16 + t16] : 0.f;
    float d = 0.f, aea = 0.f;
    int eb = prowp[n], ee = prowp[n + 1];

    for (int base = eb + 8 * half; base < ee; base += 16) {
        const int* sp = psrc + base;
        const u16* ep = EAb + (size_t)base * 16 + t16;
        float dots[8], eav[8];
        uint32 kv[8][CPL];
#pragma unroll
        for (int u = 0; u < 8; ++u) {
            int s = __builtin_nontemporal_load(sp + u);
            eav[u] = bf2f(__builtin_nontemporal_load(ep + u * 16));
            uint32 off = (uint32)s * C + l;
            float dt = qe * eav[u];
#pragma unroll
            for (int j = 0; j < CPL; ++j) {
                uint32 t = KVp[off + 32 * j];
                kv[u][j] = t;
                dt = fmaf(q[j], __uint_as_float(t & 0xffff0000u), dt);
            }
            dots[u] = dt;
        }
#pragma unroll
        for (int a = 0; a < 4; ++a) {
            float x0 = dots[2 * a], x1 = dots[2 * a + 1];
            float z = (lo16 ? x0 : x1) + __shfl_xor(lo16 ? x1 : x0, 16, 64);
            z += __shfl_xor(z, 8, 64);
            z += __shfl_xor(z, 4, 64);
            z += __shfl_xor(z, 2, 64);
            z += __shfl_xor(z, 1, 64);
            float p = __expf(z);       // lanes<16: edge 2a; lanes>=16: edge 2a+1
            float p0 = __shfl(p, 0, 32);
            float p1 = __shfl(p, 16, 32);
            d += p0 + p1;
            aea = fmaf(p0, eav[2 * a], fmaf(p1, eav[2 * a + 1], aea));
#pragma unroll
            for (int j = 0; j < CPL; ++j)
                acc[j] = fmaf(p0, __uint_as_float(kv[2 * a][j] << 16),
                         fmaf(p1, __uint_as_float(kv[2 * a + 1][j] << 16), acc[j]));
        }
    }
    d += __shfl_xor(d, 32, 64);
    aea += __shfl_xor(aea, 32, 64);
    d -= (float)((ee - eb) - deg[n]);   // remove pad contributions (exact)
    float inv = 1.f / (d + 1e-16f);
#pragma unroll
    for (int j = 0; j < CPL; ++j) {
        float a2 = acc[j] + __shfl_xor(acc[j], 32, 64);
        if (half == 0)
            Hpre[nC + l + 32 * j] = a2 * inv + SK[nC + l + 32 * j];
    }
    if (lane < 16) AEA[(uint32)n * 16 + t16] = aea * inv;
}

// ---------------- fixup layer1: H1b = bf16(relu(Hpre + AEA@We)) ------------
template <int C>
__global__ void fixup_relu_kernel(const float* __restrict__ Hpre, const float* __restrict__ AEA,
                                  const float* __restrict__ We,
                                  unsigned short* __restrict__ H1b, int NC) {
    int idx = blockIdx.x * TPB + threadIdx.x;
    if (idx >= NC) return;
    int n = idx / C, c = idx % C;
    const float* a = AEA + (size_t)n * 16;
    float s = Hpre[idx];
#pragma unroll
    for (int t = 0; t < 16; ++t) s += a[t] * We[t * C + c];
    H1b[idx] = (unsigned short)f2bf(fmaxf(s, 0.f));
}

// ---------------- fixup layer2: h = relu(...); H2p = pack(dinv*h) ----------
__global__ void fixup2_kernel(const float* __restrict__ Hpre, const float* __restrict__ AEA,
                              const float* __restrict__ We, const float* __restrict__ dinv,
                              uint32* __restrict__ H2p, int N) {
    int idx = blockIdx.x * TPB + threadIdx.x;
    if (idx >= N * 32) return;
    int n = idx >> 5, c = idx & 31;
    const float* a = AEA + (size_t)n * 16;
    float s0 = Hpre[(size_t)n * 64 + c];
    float s1 = Hpre[(size_t)n * 64 + 32 + c];
#pragma unroll
    for (int t = 0; t < 16; ++t) {
        s0 += a[t] * We[t * 64 + c];
        s1 += a[t] * We[t * 64 + 32 + c];
    }
    float dn = dinv[n];
    s0 = fmaxf(s0, 0.f) * dn;
    s1 = fmaxf(s1, 0.f) * dn;
    H2p[idx] = f2bf(s0) | (f2bf(s1) << 16);
}

// ---------------- GCN aggregation on packed dinv*h (padded CSR) ------------
__global__ __launch_bounds__(256) void gcn_agg_kernel(
    const uint32* __restrict__ H2p, const int* __restrict__ prowp,
    const int* __restrict__ psrc, const float* __restrict__ dinv,
    float* __restrict__ AGG, int N) {
    int n = blockIdx.x * 4 + (threadIdx.x >> 6);
    if (n >= N) return;
    int lane = threadIdx.x & 63, half = lane >> 5, l = lane & 31;
    float s0 = 0.f, s1 = 0.f;
    int eb = prowp[n], ee = prowp[n + 1];
    for (int base = eb + 8 * half; base < ee; base += 16) {
        const int* sp = psrc + base;
#pragma unroll
        for (int u = 0; u < 8; ++u) {
            int s = __builtin_nontemporal_load(sp + u);
            uint32 t = H2p[(uint32)s * 32 + l];   // row N is zeroed (pads)
            s0 += bf2f(t & 0xffffu);
            s1 += __uint_as_float(t & 0xffff0000u);
        }
    }
    s0 += __shfl_xor(s0, 32, 64);
    s1 += __shfl_xor(s1, 32, 64);
    if (half == 0) {
        uint32 u = H2p[(uint32)n * 32 + l];
        float dn = dinv[n];
        AGG[(uint32)n * 64 + l]      = dn * (s0 + bf2f(u & 0xffffu));
        AGG[(uint32)n * 64 + 32 + l] = dn * (s1 + __uint_as_float(u & 0xffff0000u));
    }
}

// ---------------- fp32 tiled GEMM (final 64x64 head only) ------------------
template <int CT, bool SPLIT>
__global__ __launch_bounds__(256) void gemm_kernel(
    const float* __restrict__ A, const float* __restrict__ W,
    const float* __restrict__ bias, float* __restrict__ Out,
    float* __restrict__ Out2, int N, int K, int C) {
    constexpr int TC = CT / 16;
    __shared__ float As[32][68];
    __shared__ float Bs[32][CT + 4];
    int r0 = blockIdx.x * 64, c0 = blockIdx.y * CT;
    int t = threadIdx.x;
    int tr = t >> 4, tc = t & 15;
    float acc[4][TC];
#pragma unroll
    for (int i = 0; i < 4; ++i)
#pragma unroll
        for (int j = 0; j < TC; ++j) acc[i][j] = 0.f;

    for (int kc = 0; kc < K; kc += 32) {
        int ra = t >> 2, kq = (t & 3) * 8;
        float4 a0 = {0, 0, 0, 0}, a1 = {0, 0, 0, 0};
        int r = r0 + ra;
        if (r < N) {
            const float* ap = A + (size_t)r * K + kc + kq;
            a0 = *(const float4*)ap;
            a1 = *(const float4*)(ap + 4);
        }
        As[kq + 0][ra] = a0.x; As[kq + 1][ra] = a0.y;
        As[kq + 2][ra] = a0.z; As[kq + 3][ra] = a0.w;
        As[kq + 4][ra] = a1.x; As[kq + 5][ra] = a1.y;
        As[kq + 6][ra] = a1.z; As[kq + 7][ra] = a1.w;
        constexpr int PASSES = (32 * CT) / (256 * 8);
#pragma unroll
        for (int p = 0; p < PASSES; ++p) {
            int idx = (t + p * 256) * 8;
            int k = idx / CT, c = idx % CT;
            const float* wp = W + (size_t)(kc + k) * C + c0 + c;
            float4 b0 = *(const float4*)wp;
            float4 b1 = *(const float4*)(wp + 4);
            *(float4*)&Bs[k][c] = b0;
            *(float4*)&Bs[k][c + 4] = b1;
        }
        __syncthreads();
#pragma unroll
        for (int k = 0; k < 32; ++k) {
            float4 av = *(const float4*)&As[k][tr * 4];
            float a[4] = {av.x, av.y, av.z, av.w};
#pragma unroll
            for (int u = 0; u < TC / 4; ++u) {
                float4 bv = *(const float4*)&Bs[k][tc * TC + u * 4];
                float b[4] = {bv.x, bv.y, bv.z, bv.w};
#pragma unroll
                for (int i = 0; i < 4; ++i)
#pragma unroll
                    for (int j = 0; j < 4; ++j) acc[i][u * 4 + j] += a[i] * b[j];
            }
        }
        __syncthreads();
    }
#pragma unroll
    for (int i = 0; i < 4; ++i) {
        int r = r0 + tr * 4 + i;
        if (r >= N) continue;
#pragma unroll
        for (int j = 0; j < TC; ++j) {
            int c = c0 + tc * TC + j;
            float v = acc[i][j] + bias[c];
            if (SPLIT) {
                if (c < 32) Out[(size_t)r * 32 + c] = v;
                else        Out2[(size_t)r * 32 + c - 32] = v;
            } else {
                Out[(size_t)r * C + c] = v;
            }
        }
    }
}

// ---------------------------------------------------------------------------
extern "C" void kernel_launch(void* const* d_in, const int* in_sizes, int n_in,
                              void* d_out, int out_size, void* d_ws, size_t ws_size,
                              hipStream_t stream) {
    const float* x   = (const float*)d_in[0];
    const int*   ei  = (const int*)d_in[1];
    const float* ea  = (const float*)d_in[2];
    const float* Wq1 = (const float*)d_in[3];  const float* bq1 = (const float*)d_in[4];
    const float* Wk1 = (const float*)d_in[5];  const float* bk1 = (const float*)d_in[6];
    const float* Wv1 = (const float*)d_in[7];  const float* bv1 = (const float*)d_in[8];
    const float* We1 = (const float*)d_in[9];
    const float* Ws1 = (const float*)d_in[10]; const float* bs1 = (const float*)d_in[11];
    const float* Wq2 = (const float*)d_in[12]; const float* bq2 = (const float*)d_in[13];
    const float* Wk2 = (const float*)d_in[14]; const float* bk2 = (const float*)d_in[15];
    const float* Wv2 = (const float*)d_in[16]; const float* bv2 = (const float*)d_in[17];
    const float* We2 = (const float*)d_in[18];
    const float* Ws2 = (const float*)d_in[19]; const float* bs2 = (const float*)d_in[20];
    const float* Wmu = (const float*)d_in[21]; const float* bmu = (const float*)d_in[22];
    const float* Wls = (const float*)d_in[23]; const float* bls = (const float*)d_in[24];

    int N = in_sizes[0] / 128;
    int E = in_sizes[1] / 2;
    const int* src = ei;
    const int* dst = ei + E;
    int E2max = E + 16 * N;   // padded-CSR capacity

    char* ws = (char*)d_ws;
    size_t off = 0;
    auto alloc = [&](size_t bytes) -> char* {
        char* p = ws + off;
        off = (off + bytes + 255) & ~(size_t)255;
        return p;
    };
    int*      deg    = (int*)alloc((size_t)N * 4);
    int*      prowp  = (int*)alloc((size_t)(N + 1) * 4);
    int*      cursor = (int*)alloc((size_t)N * 4);
    float*    dinv   = (float*)alloc((size_t)N * 4);
    int*      bsum   = (int*)alloc(256 * 4);
    int*      boff   = (int*)alloc(256 * 4);
    int*      psrc   = (int*)alloc((size_t)E2max * 4);
    u16*      EAb    = (u16*)alloc((size_t)E2max * 16 * 2);           // ~75 MB
    unsigned short* Wc1t = (unsigned short*)alloc(448 * 128 * 2);
    float*    bc1    = (float*)alloc(448 * 4);
    unsigned short* Wc2t = (unsigned short*)alloc(320 * 96 * 2);
    float*    bc2    = (float*)alloc(320 * 4);
    float*    Wc3    = (float*)alloc(64 * 64 * 4);
    float*    bc3    = (float*)alloc(64 * 4);
    unsigned short* xb = (unsigned short*)alloc((size_t)N * 128 * 2);
    float*    Qs   = (float*)alloc((size_t)N * 96 * 4);
    float*    QE   = (float*)alloc((size_t)N * 16 * 4);
    uint32*   KVp  = (uint32*)alloc((size_t)(N + 1) * 96 * 4);        // +1 zero row
    float*    SKb  = (float*)alloc((size_t)N * 96 * 4);
    float*    Hpre = (float*)alloc((size_t)N * 96 * 4);
    unsigned short* H1b = (unsigned short*)alloc((size_t)N * 96 * 2);
    float*    AEA  = (float*)alloc((size_t)N * 16 * 4);
    uint32*   H2p  = (uint32*)alloc((size_t)(N + 1) * 32 * 4);        // +1 zero row
    float*    AGG  = (float*)alloc((size_t)N * 64 * 4);

    (void)hipMemsetAsync(deg, 0, (size_t)N * 4, stream);
    (void)hipMemsetAsync(KVp + (size_t)N * 96, 0, 96 * 4, stream);   // layer-1 zero row
    (void)hipMemsetAsync(H2p + (size_t)N * 32, 0, 32 * 4, stream);   // gcn zero row

    int ebk = (E + TPB - 1) / TPB;
    int nb1k = (N + 1023) / 1024;
    int nbN = (N + TPB - 1) / TPB;
    hist_kernel<<<ebk, TPB, 0, stream>>>(dst, deg, E);
    scan1_kernel<<<nb1k, 1024, 0, stream>>>(deg, prowp, bsum, N);
    scan2_kernel<<<1, 64, 0, stream>>>(bsum, boff, prowp + N, nb1k);
    scan3_kernel<<<nb1k, 1024, 0, stream>>>(deg, boff, prowp, cursor, dinv, N);
    scatter_kernel<<<ebk, TPB, 0, stream>>>(src, dst, ea, cursor, psrc, EAb, E);
    padfill_kernel<<<nbN, TPB, 0, stream>>>(prowp, deg, psrc, EAb, N);
    pack_kernel<<<364, TPB, 0, stream>>>(Wq1, Wk1, Wv1, Ws1, bq1, bk1, bv1, bs1, We1,
                                         Wq2, Wk2, Wv2, Ws2, bq2, bk2, bv2, bs2, We2,
                                         Wmu, bmu, Wls, bls, x, xb, N * 128,
                                         Wc1t, bc1, Wc2t, bc2, Wc3, bc3);

    int rb = (N + 63) / 64;
    int nb4 = (N + 3) / 4;

    // ---- layer 1 ----
    mfma_gemm_kernel<<<dim3(rb, 7), 256, 0, stream>>>(xb, Wc1t, bc1, Qs, QE, KVp, SKb,
                                                      N, 128, 96);
    edge_attn_kernel<96><<<nb4, 256, 0, stream>>>(Qs, SKb, KVp, EAb, QE, prowp, deg, psrc,
                                                  Hpre, AEA, N);
    fixup_relu_kernel<96><<<(N * 96 + TPB - 1) / TPB, TPB, 0, stream>>>(Hpre, AEA, We1,
                                                                        H1b, N * 96);
    // ---- layer 2 ----
    mfma_gemm_kernel<<<dim3(rb, 5), 256, 0, stream>>>(H1b, Wc2t, bc2, Qs, QE, KVp, SKb,
                                                      N, 96, 64);
    (void)hipMemsetAsync(KVp + (size_t)N * 64, 0, 64 * 4, stream);   // layer-2 zero row
    edge_attn_kernel<64><<<nb4, 256, 0, stream>>>(Qs, SKb, KVp, EAb, QE, prowp, deg, psrc,
                                                  Hpre, AEA, N);
    fixup2_kernel<<<(N * 32 + TPB - 1) / TPB, TPB, 0, stream>>>(Hpre, AEA, We2, dinv, H2p, N);
    // ---- GCN heads ----
    gcn_agg_kernel<<<nb4, 256, 0, stream>>>(H2p, prowp, psrc, dinv, AGG, N);
    gemm_kernel<64, true><<<dim3(rb, 1), 256, 0, stream>>>(AGG, Wc3, bc3, (float*)d_out,
                                                           (float*)d_out + (size_t)N * 32,
                                                           N, 64, 64);
}

// Round 7
// 518.639 us; speedup vs baseline: 1.2014x; 1.2014x over previous
//
#include <hip/hip_runtime.h>
#include <math.h>

// ---------------------------------------------------------------------------
// GNN: 2x TransformerConv(heads=1) + fused GCNConv(mu)/GCNConv(logstd)
// N=50000, E=1.6M.
// e = ea@We enters score as (q@We^T).ea and aggregation as (sum(alpha*ea))@We.
// q@We^T folded into the packed MFMA GEMM. Edge loop touches only 16-dim bf16
// ea (CSR-streamed) + packed bf16 k/v (L2-resident gather).
// Padded CSR (multiple of 8, sentinel src=N with zero KV row, ea=0): pads
// contribute exactly exp(0)=1 to the softmax denominator -> subtract npad.
// Scatter writes are CACHED (L2 write-combining) -- nt stores on the random
// 32B/edge scatter caused 3x write amplification (R6 lesson).
// ---------------------------------------------------------------------------

#define TPB 256
typedef unsigned int uint32;
typedef unsigned short u16;
typedef __attribute__((ext_vector_type(4))) float f32x4;
typedef __attribute__((ext_vector_type(4))) uint32 u32x4;
typedef __attribute__((ext_vector_type(8))) short bf16x8;

__device__ __forceinline__ uint32 f2bf(float f) {   // RNE fp32 -> bf16 bits
    uint32 u = __float_as_uint(f);
    return (u + 0x7fffu + ((u >> 16) & 1u)) >> 16;
}
__device__ __forceinline__ float bf2f(uint32 b) { return __uint_as_float(b << 16); }

// ---------------- CSR build (padded to multiple of 8) ----------------
__global__ void hist_kernel(const int* __restrict__ dst, int* __restrict__ deg, int E) {
    int i = blockIdx.x * TPB + threadIdx.x;
    if (i < E) atomicAdd(&deg[__builtin_nontemporal_load(dst + i)], 1);
}

// pass 1: per-block inclusive scan of PADDED degrees ((deg+7)&~7)
__global__ __launch_bounds__(1024) void scan1_kernel(const int* __restrict__ deg,
                                                     int* __restrict__ prowp,
                                                     int* __restrict__ bsum, int n) {
    __shared__ int wsum[16];
    __shared__ int woff[16];
    int tid = threadIdx.x;
    int i = blockIdx.x * 1024 + tid;
    int lane = tid & 63, w = tid >> 6;
    int dg = (i < n) ? deg[i] : 0;
    int x = (dg + 7) & ~7;
    int v = x;
#pragma unroll
    for (int off = 1; off < 64; off <<= 1) {
        int t = __shfl_up(v, off, 64);
        if (lane >= off) v += t;
    }
    if (lane == 63) wsum[w] = v;
    __syncthreads();
    if (tid < 64) {
        int s = (tid < 16) ? wsum[tid] : 0;
#pragma unroll
        for (int off = 1; off < 16; off <<= 1) {
            int t = __shfl_up(s, off, 64);
            if (lane >= off) s += t;
        }
        if (tid < 16) woff[tid] = s;
    }
    __syncthreads();
    int incl = v + (w ? woff[w - 1] : 0);
    if (i < n) prowp[i] = incl;
    if (tid == 1023) bsum[blockIdx.x] = incl;
}

// pass 2: single wave scans block sums (nb <= 64); also writes total to prowp[N]
__global__ void scan2_kernel(const int* __restrict__ bsum, int* __restrict__ boff,
                             int* __restrict__ prowpN, int nb) {
    int tid = threadIdx.x;
    int x = (tid < nb) ? bsum[tid] : 0;
    int v = x;
#pragma unroll
    for (int off = 1; off < 64; off <<= 1) {
        int t = __shfl_up(v, off, 64);
        if (tid >= off) v += t;
    }
    if (tid < nb) boff[tid] = v - x;
    if (tid == nb - 1) *prowpN = v;
}

// pass 3: finalize prowp (global exclusive), cursor, dinv
__global__ __launch_bounds__(1024) void scan3_kernel(const int* __restrict__ deg,
                                                     const int* __restrict__ boff,
                                                     int* __restrict__ prowp,
                                                     int* __restrict__ cursor,
                                                     float* __restrict__ dinv, int n) {
    int i = blockIdx.x * 1024 + threadIdx.x;
    if (i < n) {
        int dg = deg[i];
        int x = (dg + 7) & ~7;
        int excl = prowp[i] - x + boff[blockIdx.x];
        prowp[i] = excl;
        cursor[i] = excl;
        dinv[i] = 1.0f / sqrtf((float)(dg + 1));
    }
}

// scatter edges into padded CSR order; permute+convert EA -> bf16 EAb
// (cached stores: L2 combines the random 32B writes)
__global__ void scatter_kernel(const int* __restrict__ src, const int* __restrict__ dst,
                               const float* __restrict__ EA,
                               int* __restrict__ cursor,
                               int* __restrict__ psrc, u16* __restrict__ EAb, int E) {
    int i = blockIdx.x * TPB + threadIdx.x;
    if (i >= E) return;
    int pos = atomicAdd(&cursor[__builtin_nontemporal_load(dst + i)], 1);
    psrc[pos] = __builtin_nontemporal_load(src + i);
    const f32x4* e4 = (const f32x4*)(EA + (size_t)i * 16);
    f32x4 a = __builtin_nontemporal_load(e4);
    f32x4 b = __builtin_nontemporal_load(e4 + 1);
    f32x4 c = __builtin_nontemporal_load(e4 + 2);
    f32x4 d = __builtin_nontemporal_load(e4 + 3);
    u32x4* o = (u32x4*)(EAb + (size_t)pos * 16);
    u32x4 lo = {f2bf(a.x) | (f2bf(a.y) << 16), f2bf(a.z) | (f2bf(a.w) << 16),
                f2bf(b.x) | (f2bf(b.y) << 16), f2bf(b.z) | (f2bf(b.w) << 16)};
    u32x4 hi = {f2bf(c.x) | (f2bf(c.y) << 16), f2bf(c.z) | (f2bf(c.w) << 16),
                f2bf(d.x) | (f2bf(d.y) << 16), f2bf(d.z) | (f2bf(d.w) << 16)};
    o[0] = lo;
    o[1] = hi;
}

// fill pad slots: psrc=N (zero KV row), ea = 0
__global__ void padfill_kernel(const int* __restrict__ prowp, const int* __restrict__ deg,
                               int* __restrict__ psrc, u16* __restrict__ EAb, int N) {
    int n = blockIdx.x * TPB + threadIdx.x;
    if (n >= N) return;
    int p = prowp[n] + deg[n], pe = prowp[n + 1];
    u32x4 z = {0u, 0u, 0u, 0u};
    for (; p < pe; ++p) {
        psrc[p] = N;
        u32x4* o = (u32x4*)(EAb + (size_t)p * 16);
        o[0] = z;
        o[1] = z;
    }
}

// ---------------- weight packing (bf16, transposed [c][k], fused QE/scale) --
__global__ void pack_kernel(
    const float* Wq1, const float* Wk1, const float* Wv1, const float* Ws1,
    const float* bq1, const float* bk1, const float* bv1, const float* bs1,
    const float* We1,
    const float* Wq2, const float* Wk2, const float* Wv2, const float* Ws2,
    const float* bq2, const float* bk2, const float* bv2, const float* bs2,
    const float* We2,
    const float* Wmu, const float* bmu, const float* Wls, const float* bls,
    const float* x, unsigned short* xb, int NX,
    unsigned short* Wc1t, float* bc1, unsigned short* Wc2t, float* bc2,
    float* Wc3, float* bc3) {
    const float s1 = 0.1020620726159658f;  // 1/sqrt(96)
    const float s2 = 0.125f;               // 1/sqrt(64)
    int gi = blockIdx.x * TPB + threadIdx.x;
    const int R0 = 448 * 128, R1 = R0 + 320 * 96, R2 = R1 + 64 * 64;
    const int R3 = R2 + 448, R4 = R3 + 320, R5 = R4 + 64;
    for (int i = gi; i < R5; i += gridDim.x * TPB) {
        if (i < R0) {                       // Wc1t[c][kk]
            int c = i / 128, kk = i % 128;
            float v = 0.f;
            if (c < 96) v = Wq1[kk * 96 + c] * s1;
            else if (c < 112) {
                int t = c - 96; float a = 0.f;
                for (int u = 0; u < 96; ++u) a += Wq1[kk * 96 + u] * We1[t * 96 + u];
                v = a * s1;
            } else if (c < 304) {
                int tt = c - 112;
                v = (tt & 1) ? Wv1[kk * 96 + (tt >> 1)] : Wk1[kk * 96 + (tt >> 1)];
            } else if (c < 400) v = Ws1[kk * 96 + (c - 304)];
            Wc1t[i] = (unsigned short)f2bf(v);
        } else if (i < R1) {                // Wc2t[c][kk]
            int j = i - R0;
            int c = j / 96, kk = j % 96;
            float v = 0.f;
            if (c < 64) v = Wq2[kk * 64 + c] * s2;
            else if (c < 80) {
                int t = c - 64; float a = 0.f;
                for (int u = 0; u < 64; ++u) a += Wq2[kk * 64 + u] * We2[t * 64 + u];
                v = a * s2;
            } else if (c < 208) {
                int tt = c - 80;
                v = (tt & 1) ? Wv2[kk * 64 + (tt >> 1)] : Wk2[kk * 64 + (tt >> 1)];
            } else if (c < 272) v = Ws2[kk * 64 + (c - 208)];
            Wc2t[j] = (unsigned short)f2bf(v);
        } else if (i < R2) {                // Wc3[k][c] fp32
            int j = i - R1;
            int k = j / 64, c = j % 64;
            Wc3[j] = (c < 32) ? Wmu[k * 32 + c] : Wls[k * 32 + (c - 32)];
        } else if (i < R3) {                // bc1
            int c = i - R2;
            float v = 0.f;
            if (c < 96) v = bq1[c] * s1;
            else if (c < 112) {
                int t = c - 96; float a = 0.f;
                for (int u = 0; u < 96; ++u) a += bq1[u] * We1[t * 96 + u];
                v = a * s1;
            } else if (c < 304) {
                int tt = c - 112;
                v = (tt & 1) ? bv1[tt >> 1] : bk1[tt >> 1];
            } else if (c < 400) v = bs1[c - 304];
            bc1[c] = v;
        } else if (i < R4) {                // bc2
            int c = i - R3;
            float v = 0.f;
            if (c < 64) v = bq2[c] * s2;
            else if (c < 80) {
                int t = c - 64; float a = 0.f;
                for (int u = 0; u < 64; ++u) a += bq2[u] * We2[t * 64 + u];
                v = a * s2;
            } else if (c < 208) {
                int tt = c - 80;
                v = (tt & 1) ? bv2[tt >> 1] : bk2[tt >> 1];
            } else if (c < 272) v = bs2[c - 208];
            bc2[c] = v;
        } else {                            // bc3
            int c = i - R4;
            bc3[c] = (c < 32) ? bmu[c] : bls[c - 32];
        }
    }
    for (int i = gi; i < NX; i += gridDim.x * TPB)
        xb[i] = (unsigned short)f2bf(x[i]);
}

// ---------------- MFMA bf16 GEMM with region epilogue ----------------------
__global__ __launch_bounds__(256) void mfma_gemm_kernel(
    const unsigned short* __restrict__ A,   // [N,K] bf16
    const unsigned short* __restrict__ Wt,  // [Cpad,K] bf16 (transposed)
    const float* __restrict__ bias,         // [Cpad]
    float* __restrict__ Qs, float* __restrict__ QE,
    uint32* __restrict__ KVp, float* __restrict__ SK,
    int N, int K, int Cq) {
    __shared__ unsigned short As[64][56];
    __shared__ unsigned short Bs[64][56];
    int r0 = blockIdx.x * 64, c0 = blockIdx.y * 64;
    int tid = threadIdx.x;
    int lane = tid & 63, w = tid >> 6;
    int wm = w >> 1, wn = w & 1;
    int l15 = lane & 15, l4 = lane >> 4;
    f32x4 zero = {0.f, 0.f, 0.f, 0.f};
    f32x4 acc[2][2] = {{zero, zero}, {zero, zero}};
    int sr = tid >> 2, sk = (tid & 3) * 8;

    for (int kc = 0; kc < K; kc += 32) {
        bf16x8 av = {};
        int ar = r0 + sr;
        if (ar < N) av = *(const bf16x8*)(A + (size_t)ar * K + kc + sk);
        *(bf16x8*)&As[sr][sk] = av;
        bf16x8 bv = *(const bf16x8*)(Wt + (size_t)(c0 + sr) * K + kc + sk);
        *(bf16x8*)&Bs[sr][sk] = bv;
        __syncthreads();
        bf16x8 af0 = *(const bf16x8*)&As[32 * wm + l15][l4 * 8];
        bf16x8 af1 = *(const bf16x8*)&As[32 * wm + 16 + l15][l4 * 8];
        bf16x8 bf0 = *(const bf16x8*)&Bs[32 * wn + l15][l4 * 8];
        bf16x8 bf1 = *(const bf16x8*)&Bs[32 * wn + 16 + l15][l4 * 8];
        acc[0][0] = __builtin_amdgcn_mfma_f32_16x16x32_bf16(af0, bf0, acc[0][0], 0, 0, 0);
        acc[0][1] = __builtin_amdgcn_mfma_f32_16x16x32_bf16(af0, bf1, acc[0][1], 0, 0, 0);
        acc[1][0] = __builtin_amdgcn_mfma_f32_16x16x32_bf16(af1, bf0, acc[1][0], 0, 0, 0);
        acc[1][1] = __builtin_amdgcn_mfma_f32_16x16x32_bf16(af1, bf1, acc[1][1], 0, 0, 0);
        __syncthreads();
    }

    int qe0 = Cq, kv0 = Cq + 16, sk0 = 3 * Cq + 16, end0 = 4 * Cq + 16;
#pragma unroll
    for (int fm = 0; fm < 2; ++fm) {
#pragma unroll
        for (int fn = 0; fn < 2; ++fn) {
            int cb = c0 + 32 * wn + 16 * fn;
            int c = cb + l15;
            float bia = bias[c];
#pragma unroll
            for (int r = 0; r < 4; ++r) {
                int row = r0 + 32 * wm + 16 * fm + l4 * 4 + r;
                float v = acc[fm][fn][r] + bia;
                float pv = __shfl_xor(v, 1, 64);
                bool ok = row < N;
                if (cb < qe0) {
                    if (ok) Qs[(size_t)row * Cq + c] = v;
                } else if (cb < kv0) {
                    if (ok) QE[(size_t)row * 16 + (c - qe0)] = v;
                } else if (cb < sk0) {
                    if (ok && !(l15 & 1)) {
                        int t = c - kv0;
                        KVp[(size_t)row * Cq + (t >> 1)] = (f2bf(v) << 16) | f2bf(pv);
                    }
                } else if (cb < end0) {
                    if (ok) SK[(size_t)row * Cq + (c - sk0)] = v;
                }
            }
        }
    }
}

// ---------------- fused edge attention (padded CSR, mask-free) -------------
template <int C>
__global__ __launch_bounds__(256) void edge_attn_kernel(
    const float* __restrict__ Qs, const float* __restrict__ SK,
    const uint32* __restrict__ KVp,
    const u16* __restrict__ EAb, const float* __restrict__ QE,
    const int* __restrict__ prowp, const int* __restrict__ deg,
    const int* __restrict__ psrc,
    float* __restrict__ Hpre, float* __restrict__ AEA, int N) {
    constexpr int CPL = C / 32;
    int n = blockIdx.x * 4 + (threadIdx.x >> 6);
    if (n >= N) return;
    int lane = threadIdx.x & 63;
    int half = lane >> 5, l = lane & 31, t16 = l & 15;
    bool lo16 = (l < 16);

    uint32 nC = (uint32)n * C;
    float q[CPL], acc[CPL];
#pragma unroll
    for (int j = 0; j < CPL; ++j) { q[j] = Qs[nC + l + 32 * j]; acc[j] = 0.f; }
    float qe = lo16 ? QE[(uint32)n * 16 + t16] : 0.f;
    float d = 0.f, aea = 0.f;
    int eb = prowp[n], ee = prowp[n + 1];

    for (int base = eb + 8 * half; base < ee; base += 16) {
        const int* sp = psrc + base;
        const u16* ep = EAb + (size_t)base * 16 + t16;
        float dots[8], eav[8];
        uint32 kv[8][CPL];
#pragma unroll
        for (int u = 0; u < 8; ++u) {
            int s = __builtin_nontemporal_load(sp + u);
            eav[u] = bf2f(__builtin_nontemporal_load(ep + u * 16));
            uint32 off = (uint32)s * C + l;
            float dt = qe * eav[u];
#pragma unroll
            for (int j = 0; j < CPL; ++j) {
                uint32 t = KVp[off + 32 * j];
                kv[u][j] = t;
                dt = fmaf(q[j], __uint_as_float(t & 0xffff0000u), dt);
            }
            dots[u] = dt;
        }
#pragma unroll
        for (int a = 0; a < 4; ++a) {
            float x0 = dots[2 * a], x1 = dots[2 * a + 1];
            float z = (lo16 ? x0 : x1) + __shfl_xor(lo16 ? x1 : x0, 16, 64);
            z += __shfl_xor(z, 8, 64);
            z += __shfl_xor(z, 4, 64);
            z += __shfl_xor(z, 2, 64);
            z += __shfl_xor(z, 1, 64);
            float p = __expf(z);       // lanes<16: edge 2a; lanes>=16: edge 2a+1
            float p0 = __shfl(p, 0, 32);
            float p1 = __shfl(p, 16, 32);
            d += p0 + p1;
            aea = fmaf(p0, eav[2 * a], fmaf(p1, eav[2 * a + 1], aea));
#pragma unroll
            for (int j = 0; j < CPL; ++j)
                acc[j] = fmaf(p0, __uint_as_float(kv[2 * a][j] << 16),
                         fmaf(p1, __uint_as_float(kv[2 * a + 1][j] << 16), acc[j]));
        }
    }
    d += __shfl_xor(d, 32, 64);
    aea += __shfl_xor(aea, 32, 64);
    d -= (float)((ee - eb) - deg[n]);   // remove pad contributions (exact)
    float inv = 1.f / (d + 1e-16f);
#pragma unroll
    for (int j = 0; j < CPL; ++j) {
        float a2 = acc[j] + __shfl_xor(acc[j], 32, 64);
        if (half == 0)
            Hpre[nC + l + 32 * j] = a2 * inv + SK[nC + l + 32 * j];
    }
    if (lane < 16) AEA[(uint32)n * 16 + t16] = aea * inv;
}

// ---------------- fixup layer1: H1b = bf16(relu(Hpre + AEA@We)) ------------
template <int C>
__global__ void fixup_relu_kernel(const float* __restrict__ Hpre, const float* __restrict__ AEA,
                                  const float* __restrict__ We,
                                  unsigned short* __restrict__ H1b, int NC) {
    int idx = blockIdx.x * TPB + threadIdx.x;
    if (idx >= NC) return;
    int n = idx / C, c = idx % C;
    const float* a = AEA + (size_t)n * 16;
    float s = Hpre[idx];
#pragma unroll
    for (int t = 0; t < 16; ++t) s += a[t] * We[t * C + c];
    H1b[idx] = (unsigned short)f2bf(fmaxf(s, 0.f));
}

// ---------------- fixup layer2: h = relu(...); H2p = pack(dinv*h) ----------
__global__ void fixup2_kernel(const float* __restrict__ Hpre, const float* __restrict__ AEA,
                              const float* __restrict__ We, const float* __restrict__ dinv,
                              uint32* __restrict__ H2p, int N) {
    int idx = blockIdx.x * TPB + threadIdx.x;
    if (idx >= N * 32) return;
    int n = idx >> 5, c = idx & 31;
    const float* a = AEA + (size_t)n * 16;
    float s0 = Hpre[(size_t)n * 64 + c];
    float s1 = Hpre[(size_t)n * 64 + 32 + c];
#pragma unroll
    for (int t = 0; t < 16; ++t) {
        s0 += a[t] * We[t * 64 + c];
        s1 += a[t] * We[t * 64 + 32 + c];
    }
    float dn = dinv[n];
    s0 = fmaxf(s0, 0.f) * dn;
    s1 = fmaxf(s1, 0.f) * dn;
    H2p[idx] = f2bf(s0) | (f2bf(s1) << 16);
}

// ---------------- GCN aggregation on packed dinv*h (padded CSR) ------------
__global__ __launch_bounds__(256) void gcn_agg_kernel(
    const uint32* __restrict__ H2p, const int* __restrict__ prowp,
    const int* __restrict__ psrc, const float* __restrict__ dinv,
    float* __restrict__ AGG, int N) {
    int n = blockIdx.x * 4 + (threadIdx.x >> 6);
    if (n >= N) return;
    int lane = threadIdx.x & 63, half = lane >> 5, l = lane & 31;
    float s0 = 0.f, s1 = 0.f;
    int eb = prowp[n], ee = prowp[n + 1];
    for (int base = eb + 8 * half; base < ee; base += 16) {
        const int* sp = psrc + base;
#pragma unroll
        for (int u = 0; u < 8; ++u) {
            int s = __builtin_nontemporal_load(sp + u);
            uint32 t = H2p[(uint32)s * 32 + l];   // row N is zeroed (pads)
            s0 += bf2f(t & 0xffffu);
            s1 += __uint_as_float(t & 0xffff0000u);
        }
    }
    s0 += __shfl_xor(s0, 32, 64);
    s1 += __shfl_xor(s1, 32, 64);
    if (half == 0) {
        uint32 u = H2p[(uint32)n * 32 + l];
        float dn = dinv[n];
        AGG[(uint32)n * 64 + l]      = dn * (s0 + bf2f(u & 0xffffu));
        AGG[(uint32)n * 64 + 32 + l] = dn * (s1 + __uint_as_float(u & 0xffff0000u));
    }
}

// ---------------- fp32 tiled GEMM (final 64x64 head only) ------------------
template <int CT, bool SPLIT>
__global__ __launch_bounds__(256) void gemm_kernel(
    const float* __restrict__ A, const float* __restrict__ W,
    const float* __restrict__ bias, float* __restrict__ Out,
    float* __restrict__ Out2, int N, int K, int C) {
    constexpr int TC = CT / 16;
    __shared__ float As[32][68];
    __shared__ float Bs[32][CT + 4];
    int r0 = blockIdx.x * 64, c0 = blockIdx.y * CT;
    int t = threadIdx.x;
    int tr = t >> 4, tc = t & 15;
    float acc[4][TC];
#pragma unroll
    for (int i = 0; i < 4; ++i)
#pragma unroll
        for (int j = 0; j < TC; ++j) acc[i][j] = 0.f;

    for (int kc = 0; kc < K; kc += 32) {
        int ra = t >> 2, kq = (t & 3) * 8;
        float4 a0 = {0, 0, 0, 0}, a1 = {0, 0, 0, 0};
        int r = r0 + ra;
        if (r < N) {
            const float* ap = A + (size_t)r * K + kc + kq;
            a0 = *(const float4*)ap;
            a1 = *(const float4*)(ap + 4);
        }
        As[kq + 0][ra] = a0.x; As[kq + 1][ra] = a0.y;
        As[kq + 2][ra] = a0.z; As[kq + 3][ra] = a0.w;
        As[kq + 4][ra] = a1.x; As[kq + 5][ra] = a1.y;
        As[kq + 6][ra] = a1.z; As[kq + 7][ra] = a1.w;
        constexpr int PASSES = (32 * CT) / (256 * 8);
#pragma unroll
        for (int p = 0; p < PASSES; ++p) {
            int idx = (t + p * 256) * 8;
            int k = idx / CT, c = idx % CT;
            const float* wp = W + (size_t)(kc + k) * C + c0 + c;
            float4 b0 = *(const float4*)wp;
            float4 b1 = *(const float4*)(wp + 4);
            *(float4*)&Bs[k][c] = b0;
            *(float4*)&Bs[k][c + 4] = b1;
        }
        __syncthreads();
#pragma unroll
        for (int k = 0; k < 32; ++k) {
            float4 av = *(const float4*)&As[k][tr * 4];
            float a[4] = {av.x, av.y, av.z, av.w};
#pragma unroll
            for (int u = 0; u < TC / 4; ++u) {
                float4 bv = *(const float4*)&Bs[k][tc * TC + u * 4];
                float b[4] = {bv.x, bv.y, bv.z, bv.w};
#pragma unroll
                for (int i = 0; i < 4; ++i)
#pragma unroll
                    for (int j = 0; j < 4; ++j) acc[i][u * 4 + j] += a[i] * b[j];
            }
        }
        __syncthreads();
    }
#pragma unroll
    for (int i = 0; i < 4; ++i) {
        int r = r0 + tr * 4 + i;
        if (r >= N) continue;
#pragma unroll
        for (int j = 0; j < TC; ++j) {
            int c = c0 + tc * TC + j;
            float v = acc[i][j] + bias[c];
            if (SPLIT) {
                if (c < 32) Out[(size_t)r * 32 + c] = v;
                else        Out2[(size_t)r * 32 + c - 32] = v;
            } else {
                Out[(size_t)r * C + c] = v;
            }
        }
    }
}

// ---------------------------------------------------------------------------
extern "C" void kernel_launch(void* const* d_in, const int* in_sizes, int n_in,
                              void* d_out, int out_size, void* d_ws, size_t ws_size,
                              hipStream_t stream) {
    const float* x   = (const float*)d_in[0];
    const int*   ei  = (const int*)d_in[1];
    const float* ea  = (const float*)d_in[2];
    const float* Wq1 = (const float*)d_in[3];  const float* bq1 = (const float*)d_in[4];
    const float* Wk1 = (const float*)d_in[5];  const float* bk1 = (const float*)d_in[6];
    const float* Wv1 = (const float*)d_in[7];  const float* bv1 = (const float*)d_in[8];
    const float* We1 = (const float*)d_in[9];
    const float* Ws1 = (const float*)d_in[10]; const float* bs1 = (const float*)d_in[11];
    const float* Wq2 = (const float*)d_in[12]; const float* bq2 = (const float*)d_in[13];
    const float* Wk2 = (const float*)d_in[14]; const float* bk2 = (const float*)d_in[15];
    const float* Wv2 = (const float*)d_in[16]; const float* bv2 = (const float*)d_in[17];
    const float* We2 = (const float*)d_in[18];
    const float* Ws2 = (const float*)d_in[19]; const float* bs2 = (const float*)d_in[20];
    const float* Wmu = (const float*)d_in[21]; const float* bmu = (const float*)d_in[22];
    const float* Wls = (const float*)d_in[23]; const float* bls = (const float*)d_in[24];

    int N = in_sizes[0] / 128;
    int E = in_sizes[1] / 2;
    const int* src = ei;
    const int* dst = ei + E;
    int E2max = E + 8 * N;   // padded-CSR capacity (pad to multiple of 8)

    char* ws = (char*)d_ws;
    size_t off = 0;
    auto alloc = [&](size_t bytes) -> char* {
        char* p = ws + off;
        off = (off + bytes + 255) & ~(size_t)255;
        return p;
    };
    int*      deg    = (int*)alloc((size_t)N * 4);
    int*      prowp  = (int*)alloc((size_t)(N + 1) * 4);
    int*      cursor = (int*)alloc((size_t)N * 4);
    float*    dinv   = (float*)alloc((size_t)N * 4);
    int*      bsum   = (int*)alloc(256 * 4);
    int*      boff   = (int*)alloc(256 * 4);
    int*      psrc   = (int*)alloc((size_t)E2max * 4);
    u16*      EAb    = (u16*)alloc((size_t)E2max * 16 * 2);
    unsigned short* Wc1t = (unsigned short*)alloc(448 * 128 * 2);
    float*    bc1    = (float*)alloc(448 * 4);
    unsigned short* Wc2t = (unsigned short*)alloc(320 * 96 * 2);
    float*    bc2    = (float*)alloc(320 * 4);
    float*    Wc3    = (float*)alloc(64 * 64 * 4);
    float*    bc3    = (float*)alloc(64 * 4);
    unsigned short* xb = (unsigned short*)alloc((size_t)N * 128 * 2);
    float*    Qs   = (float*)alloc((size_t)N * 96 * 4);
    float*    QE   = (float*)alloc((size_t)N * 16 * 4);
    uint32*   KVp  = (uint32*)alloc((size_t)(N + 1) * 96 * 4);        // +1 zero row
    float*    SKb  = (float*)alloc((size_t)N * 96 * 4);
    float*    Hpre = (float*)alloc((size_t)N * 96 * 4);
    unsigned short* H1b = (unsigned short*)alloc((size_t)N * 96 * 2);
    float*    AEA  = (float*)alloc((size_t)N * 16 * 4);
    uint32*   H2p  = (uint32*)alloc((size_t)(N + 1) * 32 * 4);        // +1 zero row
    float*    AGG  = (float*)alloc((size_t)N * 64 * 4);

    (void)hipMemsetAsync(deg, 0, (size_t)N * 4, stream);
    (void)hipMemsetAsync(KVp + (size_t)N * 96, 0, 96 * 4, stream);   // layer-1 zero row
    (void)hipMemsetAsync(H2p + (size_t)N * 32, 0, 32 * 4, stream);   // gcn zero row

    int ebk = (E + TPB - 1) / TPB;
    int nb1k = (N + 1023) / 1024;
    int nbN = (N + TPB - 1) / TPB;
    hist_kernel<<<ebk, TPB, 0, stream>>>(dst, deg, E);
    scan1_kernel<<<nb1k, 1024, 0, stream>>>(deg, prowp, bsum, N);
    scan2_kernel<<<1, 64, 0, stream>>>(bsum, boff, prowp + N, nb1k);
    scan3_kernel<<<nb1k, 1024, 0, stream>>>(deg, boff, prowp, cursor, dinv, N);
    scatter_kernel<<<ebk, TPB, 0, stream>>>(src, dst, ea, cursor, psrc, EAb, E);
    padfill_kernel<<<nbN, TPB, 0, stream>>>(prowp, deg, psrc, EAb, N);
    pack_kernel<<<364, TPB, 0, stream>>>(Wq1, Wk1, Wv1, Ws1, bq1, bk1, bv1, bs1, We1,
                                         Wq2, Wk2, Wv2, Ws2, bq2, bk2, bv2, bs2, We2,
                                         Wmu, bmu, Wls, bls, x, xb, N * 128,
                                         Wc1t, bc1, Wc2t, bc2, Wc3, bc3);

    int rb = (N + 63) / 64;
    int nb4 = (N + 3) / 4;

    // ---- layer 1 ----
    mfma_gemm_kernel<<<dim3(rb, 7), 256, 0, stream>>>(xb, Wc1t, bc1, Qs, QE, KVp, SKb,
                                                      N, 128, 96);
    edge_attn_kernel<96><<<nb4, 256, 0, stream>>>(Qs, SKb, KVp, EAb, QE, prowp, deg, psrc,
                                                  Hpre, AEA, N);
    fixup_relu_kernel<96><<<(N * 96 + TPB - 1) / TPB, TPB, 0, stream>>>(Hpre, AEA, We1,
                                                                        H1b, N * 96);
    // ---- layer 2 ----
    mfma_gemm_kernel<<<dim3(rb, 5), 256, 0, stream>>>(H1b, Wc2t, bc2, Qs, QE, KVp, SKb,
                                                      N, 96, 64);
    (void)hipMemsetAsync(KVp + (size_t)N * 64, 0, 64 * 4, stream);   // layer-2 zero row
    edge_attn_kernel<64><<<nb4, 256, 0, stream>>>(Qs, SKb, KVp, EAb, QE, prowp, deg, psrc,
                                                  Hpre, AEA, N);
    fixup2_kernel<<<(N * 32 + TPB - 1) / TPB, TPB, 0, stream>>>(Hpre, AEA, We2, dinv, H2p, N);
    // ---- GCN heads ----
    gcn_agg_kernel<<<nb4, 256, 0, stream>>>(H2p, prowp, psrc, dinv, AGG, N);
    gemm_kernel<64, true><<<dim3(rb, 1), 256, 0, stream>>>(AGG, Wc3, bc3, (float*)d_out,
                                                           (float*)d_out + (size_t)N * 32,
                                                           N, 64, 64);
}